// Round 2
// baseline (183.742 us; speedup 1.0000x reference)
//
#include <hip/hip_runtime.h>

// Problem constants (B,C,D,H,W) = (2,4,96,160,160)
#define NB 2
#define NC 4
#define ND 96
#define NH 160
#define NW 160

// Each WAVE (64 lanes) owns a 62-output-column strip x R-output-row chunk.
// Lane -> column x = strip*62 + lane - 1; lanes 0 and 63 are halo-only.
// Rolling separable Sobel: per class keep d = q[x+1]-q[x-1] (via shfl) and
// s = q[x-1]+2q[x]+q[x+1]; then gx = d[y-1]+2d[y]+d[y+1], gy = s[y+1]-s[y-1].
// sy == sz (they're identical 2D kernels), depth padding adds zero slices,
// so loss = sum(gx^2 + 2*gy^2) * SCALE  — verified exact in round 1.
constexpr int R      = 20;                          // output rows per chunk
constexpr int NCHUNK = NH / R;                      // 8
constexpr int NSTRIP = 3;                           // strips at x0 = 0, 62, 124
constexpr int NSLICE = NB * ND;                     // 192
constexpr int NTASK  = NSLICE * NSTRIP * NCHUNK;    // 4608 wave-tasks
constexpr float SCALE = 1.0f / (2.0f * 98.0f * 162.0f * 162.0f * 4.0f);

__global__ __launch_bounds__(256) void boundary_loss_kernel(
    const float* __restrict__ pred,   // (B,C,D,H,W) f32
    const int*   __restrict__ target, // (B,D,H,W) i32
    float* __restrict__ out)          // scalar, pre-zeroed
{
    const int wid  = blockIdx.x * 4 + (threadIdx.x >> 6);   // global wave id
    const int lane = threadIdx.x & 63;

    // task decode: chunk fastest (adjacent waves share halo rows -> L2 reuse)
    const int chunk = wid % NCHUNK;
    const int tmp   = wid / NCHUNK;
    const int strip = tmp % NSTRIP;
    const int slice = tmp / NSTRIP;                 // b*ND + d
    const int b     = slice / ND;
    const int d     = slice - b * ND;

    const int  x    = strip * 62 + lane - 1;
    const bool colv = (x >= 0) && (x < NW);
    const bool outm = (lane >= 1) && (lane <= 62) && (x < NW);
    const int  y0   = chunk * R;

    const size_t cs    = (size_t)ND * NH * NW;      // class stride
    const size_t pbase = ((size_t)b * NC * ND + d) * (size_t)(NH * NW);
    const size_t tbase = ((size_t)b * ND + d) * (size_t)(NH * NW);

    float smm[NC], sm[NC], dmm[NC], dm[NC];
    #pragma unroll
    for (int c = 0; c < NC; ++c) { smm[c] = sm[c] = dmm[c] = dm[c] = 0.f; }

    float acc = 0.f;

    for (int t = 0; t < R + 2; ++t) {               // stream input rows y0-1 .. y0+R
        const int gy = y0 - 1 + t;
        float q0 = 0.f, q1 = 0.f, q2 = 0.f, q3 = 0.f;
        if (colv && gy >= 0 && gy < NH) {
            const size_t off = pbase + (size_t)gy * NW + x;
            const float p0 = pred[off];
            const float p1 = pred[off + cs];
            const float p2 = pred[off + 2 * cs];
            const float p3 = pred[off + 3 * cs];
            const int   tg = target[tbase + (size_t)gy * NW + x];
            const float m  = fmaxf(fmaxf(p0, p1), fmaxf(p2, p3));
            const float e0 = __expf(p0 - m);
            const float e1 = __expf(p1 - m);
            const float e2 = __expf(p2 - m);
            const float e3 = __expf(p3 - m);
            const float inv = __builtin_amdgcn_rcpf(e0 + e1 + e2 + e3);
            q0 = e0 * inv - (tg == 0 ? 1.f : 0.f);
            q1 = e1 * inv - (tg == 1 ? 1.f : 0.f);
            q2 = e2 * inv - (tg == 2 ? 1.f : 0.f);
            q3 = e3 * inv - (tg == 3 ? 1.f : 0.f);
        }
        float q[NC] = {q0, q1, q2, q3};

        float rowacc = 0.f;
        #pragma unroll
        for (int c = 0; c < NC; ++c) {
            const float ql = __shfl_up(q[c], 1, 64);    // q at x-1
            const float qr = __shfl_down(q[c], 1, 64);  // q at x+1
            const float sn = ql + 2.f * q[c] + qr;      // horizontal smooth
            const float dn = qr - ql;                   // horizontal diff
            if (t >= 2) {
                const float gx  = dmm[c] + 2.f * dm[c] + dn;  // rows y-1,y,y+1
                const float gyv = sn - smm[c];
                rowacc += gx * gx + 2.f * gyv * gyv;
            }
            smm[c] = sm[c]; sm[c] = sn;
            dmm[c] = dm[c]; dm[c] = dn;
        }
        if (t >= 2 && outm) acc += rowacc;
    }

    // wave reduction -> one atomic per wave (no LDS, no __syncthreads)
    #pragma unroll
    for (int off = 32; off > 0; off >>= 1)
        acc += __shfl_down(acc, off, 64);
    if (lane == 0) atomicAdd(out, acc * SCALE);
}

extern "C" void kernel_launch(void* const* d_in, const int* in_sizes, int n_in,
                              void* d_out, int out_size, void* d_ws, size_t ws_size,
                              hipStream_t stream) {
    const float* pred   = (const float*)d_in[0];
    const int*   target = (const int*)d_in[1];
    float*       out    = (float*)d_out;

    // d_out is poisoned with 0xAA before every launch — zero the scalar first.
    hipMemsetAsync(out, 0, sizeof(float), stream);

    boundary_loss_kernel<<<NTASK / 4, 256, 0, stream>>>(pred, target, out);
}

// Round 3
// 153.969 us; speedup vs baseline: 1.1934x; 1.1934x over previous
//
#include <hip/hip_runtime.h>

// Problem constants (B,C,D,H,W) = (2,4,96,160,160)
#define NB 2
#define NC 4
#define ND 96
#define NH 160
#define NW 160

// Math (verified exact in rounds 1-2): sy == sz (identical 2D 3x3 kernels),
// depth padding only adds zero slices, sobel(p)-sobel(t) = sobel(q) with
// q = softmax(pred) - onehot(target), so
//   loss = sum_over_pixels(gx^2 + 2*gy^2) * SCALE
// with separable sobel: d = q[x+1]-q[x-1], s = q[x-1]+2q[x]+q[x+1],
//   gx = d[y-1]+2d[y]+d[y+1], gy = s[y+1]-s[y-1].
//
// Structure: stage q as float4 (class-interleaved) into LDS for a 64x32 tile
// (+1 halo), then each thread owns one column x 8 rows, rolling s/d state in
// registers, reading 3x ds_read_b128 per row (48B, conflict-free).
constexpr int TW = 64, TH = 32;
constexpr int SW = TW + 2, SH = TH + 2;        // 66 x 34 staged
constexpr int NSTRIP = 3;                      // x0 = 0, 64, 128 (last 32 wide)
constexpr int NCH = NH / TH;                   // 5 row chunks
constexpr int RPT = TH / 4;                    // 8 output rows per thread
constexpr float SCALE = 1.0f / (2.0f * 98.0f * 162.0f * 162.0f * 4.0f);

__global__ __launch_bounds__(256) void boundary_loss_kernel(
    const float* __restrict__ pred,   // (B,C,D,H,W) f32
    const int*   __restrict__ target, // (B,D,H,W) i32
    float* __restrict__ out)          // scalar, pre-zeroed
{
    __shared__ float4 q4[SH * SW];    // 34*66*16B = 35.9 KB -> 4 blocks/CU
    __shared__ float wsum[4];

    const int tid   = threadIdx.x;
    const int slice = blockIdx.y;              // b*ND + d
    const int b     = slice / ND;
    const int d     = slice - b * ND;
    const int tile  = blockIdx.x;
    const int strip = tile % NSTRIP;
    const int chunk = tile / NSTRIP;
    const int x0    = strip * TW;
    const int y0    = chunk * TH;

    const size_t cs    = (size_t)ND * NH * NW;                    // class stride
    const size_t pbase = ((size_t)b * NC * ND + d) * (size_t)(NH * NW);
    const size_t tbase = ((size_t)b * ND + d) * (size_t)(NH * NW);

    // ---- Stage q = softmax(pred) - onehot(target), class-interleaved ----
    for (int idx = tid; idx < SH * SW; idx += 256) {
        const int r  = idx / SW;
        const int c  = idx - r * SW;
        const int gh = y0 + r - 1;
        const int gw = x0 + c - 1;
        float4 v = make_float4(0.f, 0.f, 0.f, 0.f);
        if (gh >= 0 && gh < NH && gw >= 0 && gw < NW) {
            const size_t off = pbase + (size_t)gh * NW + gw;
            const float p0 = pred[off];
            const float p1 = pred[off + cs];
            const float p2 = pred[off + 2 * cs];
            const float p3 = pred[off + 3 * cs];
            const int   tg = target[tbase + (size_t)gh * NW + gw];
            const float m  = fmaxf(fmaxf(p0, p1), fmaxf(p2, p3));
            const float e0 = __expf(p0 - m);
            const float e1 = __expf(p1 - m);
            const float e2 = __expf(p2 - m);
            const float e3 = __expf(p3 - m);
            const float inv = 1.0f / (e0 + e1 + e2 + e3);
            v.x = e0 * inv - (tg == 0 ? 1.f : 0.f);
            v.y = e1 * inv - (tg == 1 ? 1.f : 0.f);
            v.z = e2 * inv - (tg == 2 ? 1.f : 0.f);
            v.w = e3 * inv - (tg == 3 ? 1.f : 0.f);
        }
        q4[idx] = v;
    }
    __syncthreads();

    // ---- Vertical rolling pass: 1 column x 8 rows per thread ----
    const int lane = tid & 63;
    const int grp  = tid >> 6;
    const int cc   = lane + 1;                 // staged column
    const int r0   = grp * RPT;                // staged rows r0 .. r0+RPT+1

    float smm[NC], sm[NC], dmm[NC], dm[NC];
    #pragma unroll
    for (int c = 0; c < NC; ++c) { smm[c] = sm[c] = dmm[c] = dm[c] = 0.f; }

    float acc = 0.f;
    #pragma unroll
    for (int t = 0; t < RPT + 2; ++t) {
        const int base = (r0 + t) * SW + cc;
        const float4 ql = q4[base - 1];
        const float4 qm = q4[base];
        const float4 qr = q4[base + 1];
        const float* lf = (const float*)&ql;
        const float* mf = (const float*)&qm;
        const float* rf = (const float*)&qr;
        #pragma unroll
        for (int c = 0; c < NC; ++c) {
            const float sn = lf[c] + 2.f * mf[c] + rf[c];
            const float dn = rf[c] - lf[c];
            if (t >= 2) {
                const float gx = dmm[c] + 2.f * dm[c] + dn;
                const float gy = sn - smm[c];
                acc += gx * gx + 2.f * gy * gy;
            }
            smm[c] = sm[c]; sm[c] = sn;
            dmm[c] = dm[c]; dm[c] = dn;
        }
    }
    // (columns past NW and the strip-2 overhang read zero-staged halo -> add 0)

    // ---- Block reduction -> one atomic per block ----
    #pragma unroll
    for (int off = 32; off > 0; off >>= 1)
        acc += __shfl_down(acc, off, 64);
    if (lane == 0) wsum[grp] = acc;
    __syncthreads();
    if (tid == 0) {
        const float s = wsum[0] + wsum[1] + wsum[2] + wsum[3];
        atomicAdd(out, s * SCALE);
    }
}

extern "C" void kernel_launch(void* const* d_in, const int* in_sizes, int n_in,
                              void* d_out, int out_size, void* d_ws, size_t ws_size,
                              hipStream_t stream) {
    const float* pred   = (const float*)d_in[0];
    const int*   target = (const int*)d_in[1];
    float*       out    = (float*)d_out;

    // d_out is poisoned with 0xAA before every launch — zero the scalar first.
    hipMemsetAsync(out, 0, sizeof(float), stream);

    dim3 grid(NSTRIP * NCH, NB * ND);   // 15 x 192 = 2880 blocks
    boundary_loss_kernel<<<grid, 256, 0, stream>>>(pred, target, out);
}